// Round 1
// baseline (771.299 us; speedup 1.0000x reference)
//
#include <hip/hip_runtime.h>

typedef _Float16 f16;
typedef f16 f16x8 __attribute__((ext_vector_type(8)));
typedef float f32x4 __attribute__((ext_vector_type(4)));

#define B_N 8
#define FI_N 512
#define FO_N 512

// workspace layout (bytes)
#define OFF_SMOD  0u            // [8][512] float
#define OFF_SSQ   16384u        // [8][512] float
#define OFF_DEMOD 32768u        // [8][512] float
#define OFF_WSQ   49152u        // [512][512] float
#define OFF_KEFF  1097728u      // [4][9][512][512] f16
#define OFF_XP    19972096u     // [8][66][66][512] f16 (zero-padded NHWC)
#define XP_BYTES  35684352u

// ---------------- style modulation: s, s^2 ----------------
__global__ void style_kernel(const float* __restrict__ style, const float* __restrict__ mod_w,
                             const float* __restrict__ mod_b, float* __restrict__ smod,
                             float* __restrict__ ssq) {
    int b = blockIdx.x;
    int fi = threadIdx.x;  // 512 threads
    __shared__ float st[512];
    st[fi] = style[b * 512 + fi];
    __syncthreads();
    float sum = 0.f;
    const float* mw = mod_w + (size_t)fi * 512;
    for (int d = 0; d < 512; ++d) sum += st[d] * mw[d];
    float s = sum * 0.04419417382415922f /* 512^-0.5 */ + mod_b[fi];
    smod[b * 512 + fi] = s * 0.014731391274719741f /* 4608^-0.5 */;
    ssq[b * 512 + fi] = s * s;
}

// ---------------- wsq[fo][fi] = sum_k w^2 ----------------
__global__ void wsq_kernel(const float* __restrict__ w, float* __restrict__ wsq) {
    int fo = blockIdx.x;
    int fi = threadIdx.x;  // 512
    const float* p = w + ((size_t)fo * 512 + fi) * 9;
    float s = 0.f;
#pragma unroll
    for (int k = 0; k < 9; ++k) { float v = p[k]; s += v * v; }
    wsq[fo * 512 + fi] = s;
}

// ---------------- demod[b][fo] ----------------
__global__ void demod_kernel(const float* __restrict__ ssq, const float* __restrict__ wsq,
                             float* __restrict__ demod) {
    int b = blockIdx.x >> 1;
    int fo = (blockIdx.x & 1) * 256 + threadIdx.x;
    __shared__ float sq[512];
    for (int i = threadIdx.x; i < 512; i += 256) sq[i] = ssq[b * 512 + i];
    __syncthreads();
    float sum = 0.f;
    const float* wr = wsq + (size_t)fo * 512;
    for (int fi = 0; fi < 512; ++fi) sum += sq[fi] * wr[fi];
    demod[b * 512 + fo] = rsqrtf(sum * (1.0f / 4608.0f) + 1e-8f);
}

// ---------------- Keff[c][tap][fo][fi]: fused tconv+FIR parity kernels ----------------
__global__ void keff_kernel(const float* __restrict__ w, f16* __restrict__ keff) {
    int id = blockIdx.x;  // 1024
    int fo = id >> 1;
    int fi = (id & 1) * 256 + threadIdx.x;
    float wv[9];
    const float* p = w + ((size_t)fo * 512 + fi) * 9;
#pragma unroll
    for (int k = 0; k < 9; ++k) wv[k] = p[k];
    const float g[4] = {0.25f, 0.75f, 0.75f, 0.25f};
#pragma unroll
    for (int py = 0; py < 2; ++py)
#pragma unroll
    for (int px = 0; px < 2; ++px)
#pragma unroll
    for (int ty = 0; ty < 3; ++ty)
#pragma unroll
    for (int tx = 0; tx < 3; ++tx) {
        float acc = 0.f;
#pragma unroll
        for (int jy = 0; jy < 3; ++jy) {
            int ay = jy + 1 - py + 2 * (ty - 1);
            if (ay < 0 || ay > 3) continue;
#pragma unroll
            for (int jx = 0; jx < 3; ++jx) {
                int ax = jx + 1 - px + 2 * (tx - 1);
                if (ax < 0 || ax > 3) continue;
                acc += wv[jy * 3 + jx] * g[ay] * g[ax];
            }
        }
        keff[((size_t)(((py * 2 + px) * 9 + ty * 3 + tx) * 512 + fo)) * 512 + fi] = (f16)acc;
    }
}

// ---------------- x' = x * (w_scale*s), NCHW fp32 -> padded NHWC f16 ----------------
__global__ void xp_kernel(const float* __restrict__ x, const float* __restrict__ smod,
                          f16* __restrict__ xp) {
    int id = blockIdx.x;  // 8b * 64h * 8fc = 4096
    int fc = id & 7;
    int h = (id >> 3) & 63;
    int b = id >> 9;
    int fi0 = fc * 64;
    __shared__ f16 tile[64 * 65];
    int tid = threadIdx.x;
#pragma unroll
    for (int it = 0; it < 16; ++it) {
        int e = it * 256 + tid;
        int i = e >> 6, wc = e & 63;
        float v = x[(((size_t)(b * 512 + fi0 + i)) * 64 + h) * 64 + wc];
        tile[i * 65 + wc] = (f16)(v * smod[b * 512 + fi0 + i]);
    }
    __syncthreads();
#pragma unroll
    for (int it = 0; it < 16; ++it) {
        int e = it * 256 + tid;
        int wc = e >> 6, i = e & 63;
        xp[(((size_t)(b * 66 + h + 1)) * 66 + (wc + 1)) * 512 + fi0 + i] = tile[i * 65 + wc];
    }
}

// ---------------- fused conv: implicit GEMM, 4 parity classes ----------------
__global__ __launch_bounds__(256, 2) void conv_kernel(const f16* __restrict__ keff,
                                                      const f16* __restrict__ xp,
                                                      const float* __restrict__ demod,
                                                      float* __restrict__ out) {
    int id = blockIdx.x;
    int c = id & 3;                       // parity class
    int fo0 = ((id >> 2) & 3) << 7;       // 128-row fo tile
    int S0 = ((id >> 4) & 3) << 4;        // 16 cols
    int T0 = ((id >> 6) & 7) << 3;        // 8 rows
    int b = id >> 9;
    int py = c >> 1, px = c & 1;

    __shared__ __align__(16) f16 Xwin[7200];      // [10][18][40ch]
    __shared__ __align__(16) f16 A1[2][5120];     // [128fo][40ch], double-buffered

    int tid = threadIdx.x;
    int lane = tid & 63;
    int wave = tid >> 6;
    int wm = wave >> 1, wn = wave & 1;    // wave = 64fo x 64px quadrant
    int kb = lane >> 4, lr = lane & 15;

    f32x4 acc[4][4];
#pragma unroll
    for (int m = 0; m < 4; ++m)
#pragma unroll
        for (int n = 0; n < 4; ++n) acc[m][n] = (f32x4){0.f, 0.f, 0.f, 0.f};

    for (int fi0 = 0; fi0 < 512; fi0 += 32) {
        __syncthreads();  // protect Xwin & A1[0] vs previous iter's compute
        // stage X halo window: 10x18 positions x 32ch = 720 x 16B
#pragma unroll
        for (int it = 0; it < 3; ++it) {
            int idx = it * 256 + tid;
            if (idx < 720) {
                int part = idx & 3;
                int pos = idx >> 2;
                int r = pos / 18, cc = pos - r * 18;
                const int4* src = (const int4*)(xp + ((size_t)((b * 66 + T0 + r) * 66 + (S0 + cc))) * 512 + fi0 + part * 8);
                *(int4*)(&Xwin[(r * 18 + cc) * 40 + part * 8]) = *src;
            }
        }
        // stage A for tap 0 into buf 0
#pragma unroll
        for (int it = 0; it < 2; ++it) {
            int idx = it * 256 + tid;
            int fo_r = idx >> 2, part = idx & 3;
            const int4* src = (const int4*)(keff + ((size_t)((c * 9 + 0) * 512 + fo0 + fo_r)) * 512 + fi0 + part * 8);
            *(int4*)(&A1[0][fo_r * 40 + part * 8]) = *src;
        }
#pragma unroll
        for (int tap = 0; tap < 9; ++tap) {
            __syncthreads();  // stage(tap) done; prev compute (tap-1) done before overwriting its buf
            if (tap < 8) {
#pragma unroll
                for (int it = 0; it < 2; ++it) {
                    int idx = it * 256 + tid;
                    int fo_r = idx >> 2, part = idx & 3;
                    const int4* src = (const int4*)(keff + ((size_t)((c * 9 + tap + 1) * 512 + fo0 + fo_r)) * 512 + fi0 + part * 8);
                    *(int4*)(&A1[(tap + 1) & 1][fo_r * 40 + part * 8]) = *src;
                }
            }
            int dy = tap / 3 - 1, dx = tap - (tap / 3) * 3 - 1;
            const f16* Ab = A1[tap & 1];
            f16x8 af[4], bf[4];
#pragma unroll
            for (int m = 0; m < 4; ++m)
                af[m] = *(const f16x8*)(Ab + (wm * 64 + m * 16 + lr) * 40 + kb * 8);
#pragma unroll
            for (int n = 0; n < 4; ++n) {
                int r = wn * 4 + n + dy + 1;
                int ccol = lr + dx + 1;
                bf[n] = *(const f16x8*)(&Xwin[(r * 18 + ccol) * 40 + kb * 8]);
            }
#pragma unroll
            for (int m = 0; m < 4; ++m)
#pragma unroll
                for (int n = 0; n < 4; ++n)
                    acc[m][n] = __builtin_amdgcn_mfma_f32_16x16x32_f16(af[m], bf[n], acc[m][n], 0, 0, 0);
        }
    }
    // epilogue: scale by demod, interleave by parity
#pragma unroll
    for (int m = 0; m < 4; ++m) {
#pragma unroll
        for (int j = 0; j < 4; ++j) {
            int fo = fo0 + wm * 64 + m * 16 + kb * 4 + j;  // C row = (lane>>4)*4 + j
            float dm = demod[b * 512 + fo];
#pragma unroll
            for (int n = 0; n < 4; ++n) {
                int T = T0 + wn * 4 + n;
                int S = S0 + lr;                           // C col = lane & 15
                int OY = 2 * T + py, OX = 2 * S + px;
                out[(((size_t)(b * 512 + fo)) * 128 + OY) * 128 + OX] = acc[m][n][j] * dm;
            }
        }
    }
}

extern "C" void kernel_launch(void* const* d_in, const int* in_sizes, int n_in,
                              void* d_out, int out_size, void* d_ws, size_t ws_size,
                              hipStream_t stream) {
    const float* x = (const float*)d_in[0];
    const float* style = (const float*)d_in[1];
    const float* w = (const float*)d_in[2];
    const float* mod_w = (const float*)d_in[3];
    const float* mod_b = (const float*)d_in[4];
    float* out = (float*)d_out;

    char* ws = (char*)d_ws;
    float* smod = (float*)(ws + OFF_SMOD);
    float* ssq = (float*)(ws + OFF_SSQ);
    float* demod = (float*)(ws + OFF_DEMOD);
    float* wsq = (float*)(ws + OFF_WSQ);
    f16* keff = (f16*)(ws + OFF_KEFF);
    f16* xp = (f16*)(ws + OFF_XP);

    style_kernel<<<8, 512, 0, stream>>>(style, mod_w, mod_b, smod, ssq);
    wsq_kernel<<<512, 512, 0, stream>>>(w, wsq);
    demod_kernel<<<16, 256, 0, stream>>>(ssq, wsq, demod);
    keff_kernel<<<1024, 256, 0, stream>>>(w, keff);
    hipMemsetAsync(xp, 0, XP_BYTES, stream);
    xp_kernel<<<4096, 256, 0, stream>>>(x, smod, xp);
    conv_kernel<<<4096, 256, 0, stream>>>(keff, xp, demod, out);
}

// Round 2
// 596.656 us; speedup vs baseline: 1.2927x; 1.2927x over previous
//
#include <hip/hip_runtime.h>

typedef _Float16 f16;
typedef f16 f16x8 __attribute__((ext_vector_type(8)));
typedef float f32x4 __attribute__((ext_vector_type(4)));

// ---------------- shared small-kernel workspace ----------------
#define OFF_SMOD  0u            // [8][512] float
#define OFF_SSQ   16384u        // [8][512] float
#define OFF_DEMOD 32768u        // [8][512] float
#define OFF_WSQ   49152u        // [512][512] float
// --- new path layout ---
#define OFF_WPAR  1097728u      // [9][512][512] f16
#define OFF_XP2   5816320u      // [8][66][66][512] f16
#define OFF_YP    41500672u     // [4][8][512][68][68] f16 parity planes
#define WS_NEW    193019904u
// --- old (fallback) path layout ---
#define OFF_KEFF  1097728u      // [4][9][512][512] f16
#define OFF_XP1   19972096u     // [8][66][66][512] f16
#define XP_BYTES  35684352u

// ---------------- style modulation: s, s^2 ----------------
__global__ void style_kernel(const float* __restrict__ style, const float* __restrict__ mod_w,
                             const float* __restrict__ mod_b, float* __restrict__ smod,
                             float* __restrict__ ssq) {
    int b = blockIdx.x;
    int fi = threadIdx.x;  // 512 threads
    __shared__ float st[512];
    st[fi] = style[b * 512 + fi];
    __syncthreads();
    float sum = 0.f;
    const float* mw = mod_w + (size_t)fi * 512;
    for (int d = 0; d < 512; ++d) sum += st[d] * mw[d];
    float s = sum * 0.04419417382415922f /* 512^-0.5 */ + mod_b[fi];
    smod[b * 512 + fi] = s * 0.014731391274719741f /* 4608^-0.5 */;
    ssq[b * 512 + fi] = s * s;
}

// ---------------- wsq[fo][fi] = sum_k w^2 ----------------
__global__ void wsq_kernel(const float* __restrict__ w, float* __restrict__ wsq) {
    int fo = blockIdx.x;
    int fi = threadIdx.x;  // 512
    const float* p = w + ((size_t)fo * 512 + fi) * 9;
    float s = 0.f;
#pragma unroll
    for (int k = 0; k < 9; ++k) { float v = p[k]; s += v * v; }
    wsq[fo * 512 + fi] = s;
}

// ---------------- demod[b][fo] ----------------
__global__ void demod_kernel(const float* __restrict__ ssq, const float* __restrict__ wsq,
                             float* __restrict__ demod) {
    int b = blockIdx.x >> 1;
    int fo = (blockIdx.x & 1) * 256 + threadIdx.x;
    __shared__ float sq[512];
    for (int i = threadIdx.x; i < 512; i += 256) sq[i] = ssq[b * 512 + i];
    __syncthreads();
    float sum = 0.f;
    const float* wr = wsq + (size_t)fo * 512;
    for (int fi = 0; fi < 512; ++fi) sum += sq[fi] * wr[fi];
    demod[b * 512 + fo] = rsqrtf(sum * (1.0f / 4608.0f) + 1e-8f);
}

// ---------------- x' = x * (w_scale*s), NCHW fp32 -> padded NHWC f16 ----------------
__global__ void xp_kernel(const float* __restrict__ x, const float* __restrict__ smod,
                          f16* __restrict__ xp) {
    int id = blockIdx.x;  // 8b * 64h * 8fc = 4096
    int fc = id & 7;
    int h = (id >> 3) & 63;
    int b = id >> 9;
    int fi0 = fc * 64;
    __shared__ f16 tile[64 * 65];
    int tid = threadIdx.x;
#pragma unroll
    for (int it = 0; it < 16; ++it) {
        int e = it * 256 + tid;
        int i = e >> 6, wc = e & 63;
        float v = x[(((size_t)(b * 512 + fi0 + i)) * 64 + h) * 64 + wc];
        tile[i * 65 + wc] = (f16)(v * smod[b * 512 + fi0 + i]);
    }
    __syncthreads();
#pragma unroll
    for (int it = 0; it < 16; ++it) {
        int e = it * 256 + tid;
        int wc = e >> 6, i = e & 63;
        xp[(((size_t)(b * 66 + h + 1)) * 66 + (wc + 1)) * 512 + fi0 + i] = tile[i * 65 + wc];
    }
}

// =================== NEW PATH ===================

// wpar[slot][fo][fi]: per-parity-class tconv taps (f16 cast of w elements)
__global__ void wpar_kernel(const float* __restrict__ w, f16* __restrict__ wpar) {
    // slot -> w flat index (ky*3+kx):
    // c0(ee): (2,2),(2,0),(0,2),(0,0); c1(eo): (2,1),(0,1); c2(oe): (1,2),(1,0); c3(oo): (1,1)
    const int wi_[9] = {8, 6, 2, 0, 7, 1, 5, 3, 4};
    int fo = blockIdx.x;
#pragma unroll
    for (int half = 0; half < 2; ++half) {
        int fi = half * 256 + threadIdx.x;
        const float* p = w + ((size_t)fo * 512 + fi) * 9;
#pragma unroll
        for (int s = 0; s < 9; ++s)
            wpar[((size_t)(s * 512 + fo)) * 512 + fi] = (f16)p[wi_[s]];
    }
}

// zero the pad ring of each parity plane slab [68][68]
__global__ void ring_kernel(f16* __restrict__ P) {
    int slab = blockIdx.x;         // (c*8+b)*512+fo, 16384 total
    int c = slab >> 12;
    int tmax = 64 - (c >> 1), smax = 64 - (c & 1);
    f16* base = P + (size_t)slab * (68 * 68);
    for (int idx = threadIdx.x; idx < 68 * 68; idx += 256) {
        int tix = idx / 68, six = idx - tix * 68;
        if (tix < 1 || tix > tmax + 1 || six < 1 || six > smax + 1) base[idx] = (f16)0.f;
    }
}

// pass 1: parity-decomposed transposed conv, y -> f16 parity planes
__global__ __launch_bounds__(256, 2) void tconv_kernel(const f16* __restrict__ wpar,
                                                       const f16* __restrict__ xp,
                                                       f16* __restrict__ P) {
    const int nt_[4] = {4, 2, 2, 1};
    const int sb_[4] = {0, 4, 6, 8};
    const int dy_[9] = {-1, -1, 0, 0, -1, 0, 0, 0, 0};
    const int dx_[9] = {-1, 0, -1, 0, 0, 0, -1, 0, 0};

    int bid = blockIdx.x;          // 8b * 4fo * 153 class-tiles = 4896
    int b = bid / 612;
    int rem = bid - b * 612;
    int fg = rem / 153;
    int fo0 = fg << 7;
    int q = rem - fg * 153;
    int c, tt, ss;
    if (q < 45)       { c = 0; tt = q / 5;  ss = q - tt * 5; }
    else if (q < 81)  { int tq = q - 45;  c = 1; tt = tq >> 2; ss = tq & 3; }
    else if (q < 121) { int tq = q - 81;  c = 2; tt = tq / 5;  ss = tq - tt * 5; }
    else              { int tq = q - 121; c = 3; tt = tq >> 2; ss = tq & 3; }
    int T0 = tt << 3, S0 = ss << 4;
    int nt = nt_[c], sb = sb_[c];
    int py = c >> 1, px = c & 1;
    int tmax = 64 - py, smax = 64 - px;

    __shared__ __align__(16) f16 Xwin[9 * 17 * 40];   // [9 rows][17 cols][40ch]
    __shared__ __align__(16) f16 A1[2][5120];         // [128fo][40ch] double-buffered

    int tid = threadIdx.x;
    int lane = tid & 63;
    int wave = tid >> 6;
    int wm = wave >> 1, wn = wave & 1;
    int kb = lane >> 4, lr = lane & 15;

    f32x4 acc[4][4];
#pragma unroll
    for (int m = 0; m < 4; ++m)
#pragma unroll
        for (int n = 0; n < 4; ++n) acc[m][n] = (f32x4){0.f, 0.f, 0.f, 0.f};

    for (int fi0 = 0; fi0 < 512; fi0 += 32) {
        __syncthreads();
        // stage X window: 9x17 positions x 32ch = 612 x 16B (bounds-masked)
#pragma unroll
        for (int it = 0; it < 3; ++it) {
            int idx = it * 256 + tid;
            if (idx < 612) {
                int part = idx & 3;
                int pos = idx >> 2;
                int r = pos / 17, cc = pos - r * 17;
                int gr = T0 + r, gc = S0 + cc;
                int4 v = {0, 0, 0, 0};
                if (gr < 66 && gc < 66)
                    v = *(const int4*)(xp + ((size_t)((b * 66 + gr) * 66 + gc)) * 512 + fi0 + part * 8);
                *(int4*)(&Xwin[pos * 40 + part * 8]) = v;
            }
        }
        // stage A for first tap into buf 0
#pragma unroll
        for (int it = 0; it < 2; ++it) {
            int idx = it * 256 + tid;
            int fo_r = idx >> 2, part = idx & 3;
            *(int4*)(&A1[0][fo_r * 40 + part * 8]) =
                *(const int4*)(wpar + ((size_t)(sb * 512 + fo0 + fo_r)) * 512 + fi0 + part * 8);
        }
        for (int tap = 0; tap < nt; ++tap) {
            __syncthreads();
            if (tap + 1 < nt) {
#pragma unroll
                for (int it = 0; it < 2; ++it) {
                    int idx = it * 256 + tid;
                    int fo_r = idx >> 2, part = idx & 3;
                    *(int4*)(&A1[(tap + 1) & 1][fo_r * 40 + part * 8]) =
                        *(const int4*)(wpar + ((size_t)((sb + tap + 1) * 512 + fo0 + fo_r)) * 512 + fi0 + part * 8);
                }
            }
            int dy = dy_[sb + tap], dx = dx_[sb + tap];
            const f16* Ab = A1[tap & 1];
            f16x8 af[4], bf[4];
#pragma unroll
            for (int m = 0; m < 4; ++m)
                af[m] = *(const f16x8*)(Ab + (wm * 64 + m * 16 + lr) * 40 + kb * 8);
#pragma unroll
            for (int n = 0; n < 4; ++n)
                bf[n] = *(const f16x8*)(&Xwin[((wn * 4 + n + dy + 1) * 17 + (lr + dx + 1)) * 40 + kb * 8]);
#pragma unroll
            for (int m = 0; m < 4; ++m)
#pragma unroll
                for (int n = 0; n < 4; ++n)
                    acc[m][n] = __builtin_amdgcn_mfma_f32_16x16x32_f16(af[m], bf[n], acc[m][n], 0, 0, 0);
        }
    }
    // epilogue: store y (f16) into parity plane, masked at class edges
    size_t cslab = (size_t)((py * 2 + px) * 8 + b) * 512;
#pragma unroll
    for (int m = 0; m < 4; ++m) {
#pragma unroll
        for (int j = 0; j < 4; ++j) {
            int fo = fo0 + wm * 64 + m * 16 + kb * 4 + j;
            f16* row = P + ((cslab + fo) * 68) * 68;
#pragma unroll
            for (int n = 0; n < 4; ++n) {
                int t = T0 + wn * 4 + n;
                int s = S0 + lr;
                if (t <= tmax && s <= smax)
                    row[(size_t)(t + 1) * 68 + (s + 1)] = (f16)acc[m][n][j];
            }
        }
    }
}

// pass 2: separable FIR [.25 .75 .75 .25]^2 over y (parity-plane gather) + demod
__global__ __launch_bounds__(256) void fir_kernel(const f16* __restrict__ P,
                                                  const float* __restrict__ demod,
                                                  float* __restrict__ out) {
    int bid = blockIdx.x;          // 8b * 512fo * 8rc = 32768
    int rc = bid & 7;
    int fo = (bid >> 3) & 511;
    int b = bid >> 12;
    int OY0 = rc * 16;

    __shared__ f16 yr[19 * 132];
    int tid = threadIdx.x;
#pragma unroll
    for (int it = 0; it < 10; ++it) {
        int idx = it * 256 + tid;
        if (idx < 19 * 132) {
            int rr = idx / 132, cidx = idx - rr * 132;
            int oy = OY0 - 1 + rr;
            int ox = cidx - 1;
            f16 v = (f16)0.f;
            if (cidx < 131) {
                int pyy = oy & 1, pxx = ox & 1;
                int t = oy >> 1, s = ox >> 1;
                v = P[(((size_t)((pyy * 2 + pxx) * 8 + b) * 512 + fo) * 68 + (t + 1)) * 68 + (s + 1)];
            }
            yr[rr * 132 + cidx] = v;
        }
    }
    __syncthreads();
    float dm = demod[b * 512 + fo];
    int OX = tid & 127;
    int rg = tid >> 7;
    const float f4[4] = {0.25f, 0.75f, 0.75f, 0.25f};
#pragma unroll
    for (int i = 0; i < 8; ++i) {
        int rl = rg * 8 + i;
        float acc2 = 0.f;
#pragma unroll
        for (int a = 0; a < 4; ++a) {
            float h = 0.f;
#pragma unroll
            for (int bb = 0; bb < 4; ++bb)
                h += f4[bb] * (float)yr[(rl + a) * 132 + OX + bb];
            acc2 += f4[a] * h;
        }
        out[(((size_t)(b * 512 + fo)) * 128 + OY0 + rl) * 128 + OX] = acc2 * dm;
    }
}

// =================== OLD (fallback) PATH ===================

__global__ void keff_kernel(const float* __restrict__ w, f16* __restrict__ keff) {
    int id = blockIdx.x;
    int fo = id >> 1;
    int fi = (id & 1) * 256 + threadIdx.x;
    float wv[9];
    const float* p = w + ((size_t)fo * 512 + fi) * 9;
#pragma unroll
    for (int k = 0; k < 9; ++k) wv[k] = p[k];
    const float g[4] = {0.25f, 0.75f, 0.75f, 0.25f};
#pragma unroll
    for (int py = 0; py < 2; ++py)
#pragma unroll
    for (int px = 0; px < 2; ++px)
#pragma unroll
    for (int ty = 0; ty < 3; ++ty)
#pragma unroll
    for (int tx = 0; tx < 3; ++tx) {
        float acc = 0.f;
#pragma unroll
        for (int jy = 0; jy < 3; ++jy) {
            int ay = jy + 1 - py + 2 * (ty - 1);
            if (ay < 0 || ay > 3) continue;
#pragma unroll
            for (int jx = 0; jx < 3; ++jx) {
                int ax = jx + 1 - px + 2 * (tx - 1);
                if (ax < 0 || ax > 3) continue;
                acc += wv[jy * 3 + jx] * g[ay] * g[ax];
            }
        }
        keff[((size_t)(((py * 2 + px) * 9 + ty * 3 + tx) * 512 + fo)) * 512 + fi] = (f16)acc;
    }
}

__global__ __launch_bounds__(256, 2) void conv_kernel(const f16* __restrict__ keff,
                                                      const f16* __restrict__ xp,
                                                      const float* __restrict__ demod,
                                                      float* __restrict__ out) {
    int id = blockIdx.x;
    int c = id & 3;
    int fo0 = ((id >> 2) & 3) << 7;
    int S0 = ((id >> 4) & 3) << 4;
    int T0 = ((id >> 6) & 7) << 3;
    int b = id >> 9;
    int py = c >> 1, px = c & 1;

    __shared__ __align__(16) f16 Xwin[7200];
    __shared__ __align__(16) f16 A1[2][5120];

    int tid = threadIdx.x;
    int lane = tid & 63;
    int wave = tid >> 6;
    int wm = wave >> 1, wn = wave & 1;
    int kb = lane >> 4, lr = lane & 15;

    f32x4 acc[4][4];
#pragma unroll
    for (int m = 0; m < 4; ++m)
#pragma unroll
        for (int n = 0; n < 4; ++n) acc[m][n] = (f32x4){0.f, 0.f, 0.f, 0.f};

    for (int fi0 = 0; fi0 < 512; fi0 += 32) {
        __syncthreads();
#pragma unroll
        for (int it = 0; it < 3; ++it) {
            int idx = it * 256 + tid;
            if (idx < 720) {
                int part = idx & 3;
                int pos = idx >> 2;
                int r = pos / 18, cc = pos - r * 18;
                const int4* src = (const int4*)(xp + ((size_t)((b * 66 + T0 + r) * 66 + (S0 + cc))) * 512 + fi0 + part * 8);
                *(int4*)(&Xwin[(r * 18 + cc) * 40 + part * 8]) = *src;
            }
        }
#pragma unroll
        for (int it = 0; it < 2; ++it) {
            int idx = it * 256 + tid;
            int fo_r = idx >> 2, part = idx & 3;
            const int4* src = (const int4*)(keff + ((size_t)((c * 9 + 0) * 512 + fo0 + fo_r)) * 512 + fi0 + part * 8);
            *(int4*)(&A1[0][fo_r * 40 + part * 8]) = *src;
        }
#pragma unroll
        for (int tap = 0; tap < 9; ++tap) {
            __syncthreads();
            if (tap < 8) {
#pragma unroll
                for (int it = 0; it < 2; ++it) {
                    int idx = it * 256 + tid;
                    int fo_r = idx >> 2, part = idx & 3;
                    const int4* src = (const int4*)(keff + ((size_t)((c * 9 + tap + 1) * 512 + fo0 + fo_r)) * 512 + fi0 + part * 8);
                    *(int4*)(&A1[(tap + 1) & 1][fo_r * 40 + part * 8]) = *src;
                }
            }
            int dy = tap / 3 - 1, dx = tap - (tap / 3) * 3 - 1;
            const f16* Ab = A1[tap & 1];
            f16x8 af[4], bf[4];
#pragma unroll
            for (int m = 0; m < 4; ++m)
                af[m] = *(const f16x8*)(Ab + (wm * 64 + m * 16 + lr) * 40 + kb * 8);
#pragma unroll
            for (int n = 0; n < 4; ++n) {
                int r = wn * 4 + n + dy + 1;
                int ccol = lr + dx + 1;
                bf[n] = *(const f16x8*)(&Xwin[(r * 18 + ccol) * 40 + kb * 8]);
            }
#pragma unroll
            for (int m = 0; m < 4; ++m)
#pragma unroll
                for (int n = 0; n < 4; ++n)
                    acc[m][n] = __builtin_amdgcn_mfma_f32_16x16x32_f16(af[m], bf[n], acc[m][n], 0, 0, 0);
        }
    }
#pragma unroll
    for (int m = 0; m < 4; ++m) {
#pragma unroll
        for (int j = 0; j < 4; ++j) {
            int fo = fo0 + wm * 64 + m * 16 + kb * 4 + j;
            float dm = demod[b * 512 + fo];
#pragma unroll
            for (int n = 0; n < 4; ++n) {
                int T = T0 + wn * 4 + n;
                int S = S0 + lr;
                int OY = 2 * T + py, OX = 2 * S + px;
                out[(((size_t)(b * 512 + fo)) * 128 + OY) * 128 + OX] = acc[m][n][j] * dm;
            }
        }
    }
}

extern "C" void kernel_launch(void* const* d_in, const int* in_sizes, int n_in,
                              void* d_out, int out_size, void* d_ws, size_t ws_size,
                              hipStream_t stream) {
    const float* x = (const float*)d_in[0];
    const float* style = (const float*)d_in[1];
    const float* w = (const float*)d_in[2];
    const float* mod_w = (const float*)d_in[3];
    const float* mod_b = (const float*)d_in[4];
    float* out = (float*)d_out;

    char* ws = (char*)d_ws;
    float* smod = (float*)(ws + OFF_SMOD);
    float* ssq = (float*)(ws + OFF_SSQ);
    float* demod = (float*)(ws + OFF_DEMOD);
    float* wsq = (float*)(ws + OFF_WSQ);

    style_kernel<<<8, 512, 0, stream>>>(style, mod_w, mod_b, smod, ssq);
    wsq_kernel<<<512, 512, 0, stream>>>(w, wsq);
    demod_kernel<<<16, 256, 0, stream>>>(ssq, wsq, demod);

    if (ws_size >= (size_t)WS_NEW) {
        f16* wpar = (f16*)(ws + OFF_WPAR);
        f16* xp = (f16*)(ws + OFF_XP2);
        f16* P = (f16*)(ws + OFF_YP);
        wpar_kernel<<<512, 256, 0, stream>>>(w, wpar);
        hipMemsetAsync(xp, 0, XP_BYTES, stream);
        xp_kernel<<<4096, 256, 0, stream>>>(x, smod, xp);
        ring_kernel<<<16384, 256, 0, stream>>>(P);
        tconv_kernel<<<4896, 256, 0, stream>>>(wpar, xp, P);
        fir_kernel<<<32768, 256, 0, stream>>>(P, demod, out);
    } else {
        f16* keff = (f16*)(ws + OFF_KEFF);
        f16* xp = (f16*)(ws + OFF_XP1);
        keff_kernel<<<1024, 256, 0, stream>>>(w, keff);
        hipMemsetAsync(xp, 0, XP_BYTES, stream);
        xp_kernel<<<4096, 256, 0, stream>>>(x, smod, xp);
        conv_kernel<<<4096, 256, 0, stream>>>(keff, xp, demod, out);
    }
}

// Round 3
// 401.354 us; speedup vs baseline: 1.9217x; 1.4866x over previous
//
#include <hip/hip_runtime.h>

typedef _Float16 f16;
typedef f16 f16x8 __attribute__((ext_vector_type(8)));
typedef float f32x4 __attribute__((ext_vector_type(4)));

// workspace layout (bytes); proven ws_size >= 193,019,904 (round-2 new path ran)
#define OFF_SMOD  0u            // [8][512] float
#define OFF_SSQ   16384u        // [8][512] float
#define OFF_DEMOD 32768u        // [8][512] float
#define OFF_WSQ   49152u        // [512][512] float
#define OFF_WPAR  1097728u      // [9][16][512][32] f16 (slot, fi-chunk, fo, ch)
#define OFF_XP    5816320u      // [8*4356 + 1][512] f16 (flat padded planes + 1 zero guard row)
#define XP_BYTES  35685376u     // (8*4356+1)*512*2
#define OFF_YP    41501696u     // [4][8][512][67][68] f16 parity planes
#define WS_NEED   190792704u
#define PLANE     4556          // 67*68

// ---------------- style modulation: s, s^2 ----------------
__global__ void style_kernel(const float* __restrict__ style, const float* __restrict__ mod_w,
                             const float* __restrict__ mod_b, float* __restrict__ smod,
                             float* __restrict__ ssq) {
    int b = blockIdx.x;
    int fi = threadIdx.x;  // 512 threads
    __shared__ float st[512];
    st[fi] = style[b * 512 + fi];
    __syncthreads();
    float sum = 0.f;
    const float* mw = mod_w + (size_t)fi * 512;
    for (int d = 0; d < 512; ++d) sum += st[d] * mw[d];
    float s = sum * 0.04419417382415922f /* 512^-0.5 */ + mod_b[fi];
    smod[b * 512 + fi] = s * 0.014731391274719741f /* 4608^-0.5 */;
    ssq[b * 512 + fi] = s * s;
}

// ---------------- wsq[fo][fi] = sum_k w^2 ----------------
__global__ void wsq_kernel(const float* __restrict__ w, float* __restrict__ wsq) {
    int fo = blockIdx.x;
    int fi = threadIdx.x;  // 512
    const float* p = w + ((size_t)fo * 512 + fi) * 9;
    float s = 0.f;
#pragma unroll
    for (int k = 0; k < 9; ++k) { float v = p[k]; s += v * v; }
    wsq[fo * 512 + fi] = s;
}

// ---------------- demod[b][fo] ----------------
__global__ void demod_kernel(const float* __restrict__ ssq, const float* __restrict__ wsq,
                             float* __restrict__ demod) {
    int b = blockIdx.x >> 1;
    int fo = (blockIdx.x & 1) * 256 + threadIdx.x;
    __shared__ float sq[512];
    for (int i = threadIdx.x; i < 512; i += 256) sq[i] = ssq[b * 512 + i];
    __syncthreads();
    float sum = 0.f;
    const float* wr = wsq + (size_t)fo * 512;
    for (int fi = 0; fi < 512; ++fi) sum += sq[fi] * wr[fi];
    demod[b * 512 + fo] = rsqrtf(sum * (1.0f / 4608.0f) + 1e-8f);
}

// ---------------- x' = x * (w_scale*s), NCHW fp32 -> padded NHWC f16 ----------------
__global__ void xp_kernel(const float* __restrict__ x, const float* __restrict__ smod,
                          f16* __restrict__ xp) {
    int id = blockIdx.x;  // 8b * 64h * 8fc = 4096
    int fc = id & 7;
    int h = (id >> 3) & 63;
    int b = id >> 9;
    int fi0 = fc * 64;
    __shared__ f16 tile[64 * 65];
    int tid = threadIdx.x;
#pragma unroll
    for (int it = 0; it < 16; ++it) {
        int e = it * 256 + tid;
        int i = e >> 6, wc = e & 63;
        float v = x[(((size_t)(b * 512 + fi0 + i)) * 64 + h) * 64 + wc];
        tile[i * 65 + wc] = (f16)(v * smod[b * 512 + fi0 + i]);
    }
    __syncthreads();
#pragma unroll
    for (int it = 0; it < 16; ++it) {
        int e = it * 256 + tid;
        int wc = e >> 6, i = e & 63;
        xp[((size_t)(b * 4356 + (h + 1) * 66 + (wc + 1))) * 512 + fi0 + i] = tile[i * 65 + wc];
    }
}

// ---------------- wpar2[slot][fi-chunk][fo][32ch]: A tiled for coalesced frag loads ----------------
__global__ void wpar2_kernel(const float* __restrict__ w, f16* __restrict__ wpar2) {
    // slot -> w flat index (ky*3+kx):
    // c0(ee): (2,2),(2,0),(0,2),(0,0); c1(eo): (2,1),(0,1); c2(oe): (1,2),(1,0); c3(oo): (1,1)
    const int wi_[9] = {8, 6, 2, 0, 7, 1, 5, 3, 4};
    int fo = blockIdx.x;
#pragma unroll
    for (int half = 0; half < 2; ++half) {
        int fi = half * 256 + threadIdx.x;
        const float* p = w + ((size_t)fo * 512 + fi) * 9;
        int fc = fi >> 5, ch = fi & 31;
#pragma unroll
        for (int s = 0; s < 9; ++s)
            wpar2[(((size_t)s * 16 + fc) * 512 + fo) * 32 + ch] = (f16)p[wi_[s]];
    }
}

// ---------------- zero row 0 and col 0 of each parity plane ----------------
__global__ void ring2_kernel(f16* __restrict__ P) {
    int idx = blockIdx.x * 256 + threadIdx.x;
    if (idx >= 16384 * 133) return;
    int slab = idx / 133, r = idx - slab * 133;
    f16* base = P + (size_t)slab * PLANE;
    if (r < 68) base[r] = (f16)0.f;          // row 0
    else base[(r - 67) * 68] = (f16)0.f;     // col 0, rows 1..65
}

// ---------------- pass 1: flattened-N shifted implicit GEMM per parity class ----------------
template <int C>
__device__ __forceinline__ void tconv_body(const f16* __restrict__ wpar2, const f16* __restrict__ xp,
                                           f16* __restrict__ P, f16* Xs, int b, int fg, int n0t) {
    constexpr int NT   = (C == 0) ? 4 : (C == 3) ? 1 : 2;
    constexpr int SB   = (C == 0) ? 0 : (C == 1) ? 4 : (C == 2) ? 6 : 8;
    constexpr int LB   = (C <= 1) ? 67 : (C == 2) ? 1 : 0;    // local-row base
    constexpr int WOFF = (C <= 1) ? 0 : (C == 2) ? 66 : 67;   // window start rel n0
    constexpr int WLEN = (C <= 1) ? 195 : (C == 2) ? 129 : 128;
    constexpr int CH4  = WLEN * 4;
    constexpr int offs[4] = {(C == 0) ? -67 : (C == 1) ? -66 : (C == 2) ? -1 : 0,
                             (C == 0) ? -66 : 0, -1, 0};

    int tid = threadIdx.x, lane = tid & 63, wave = tid >> 6;
    int wm = wave >> 1, wn = wave & 1, kb = lane >> 4, lr = lane & 15;
    int n0 = n0t << 7, fo0 = fg << 7;
    int WB = b * 4356 + n0 + WOFF;
    int bmax = b * 4356 + 4356;   // per-b guard row (zeroed)

    f32x4 acc[4][4];
#pragma unroll
    for (int m = 0; m < 4; ++m)
#pragma unroll
        for (int n = 0; n < 4; ++n) acc[m][n] = (f32x4){0.f, 0.f, 0.f, 0.f};

    int4 xr[4];
    f16x8 afA[4], afB[4];

    // A frag loads: coalesced 1KB/wave from wpar2 tiles, straight to registers.
    const f16* abase = wpar2 + ((size_t)(fo0 + wm * 64 + lr)) * 32 + (size_t)kb * 8;
    auto loadA = [&](int q, f16x8* dst) {
        int fc = q / NT, tap = q - fc * NT;
        const f16* p = abase + (size_t)((SB + tap) * 16 + fc) * (512 * 32);
#pragma unroll
        for (int m = 0; m < 4; ++m) dst[m] = *(const f16x8*)(p + m * 16 * 32);
    };
    auto loadX = [&](int k) {
        int fi0 = k * 32;
#pragma unroll
        for (int it = 0; it < 4; ++it) {
            int idx = it * 256 + tid;
            int4 v = {0, 0, 0, 0};
            if (idx < CH4) {
                int r = idx >> 2, part = idx & 3;
                int pr = WB + r;
                if (pr <= bmax) v = *(const int4*)(xp + ((size_t)pr * 512 + fi0 + part * 8));
            }
            xr[it] = v;
        }
    };
    auto writeX = [&]() {
#pragma unroll
        for (int it = 0; it < 4; ++it) {
            int idx = it * 256 + tid;
            if (idx < CH4) {
                int r = idx >> 2, part = idx & 3;
                *(int4*)((char*)Xs + ((((r * 4 + part) ^ (r & 7)) << 4))) = xr[it];
            }
        }
    };

    loadA(0, afA);
    loadX(0);
    for (int k = 0; k < 16; ++k) {
        __syncthreads();            // previous taps done reading Xs
        writeX();
        __syncthreads();
        if (k < 15) loadX(k + 1);   // issue next K-step's X loads; land after taps
#pragma unroll
        for (int tap = 0; tap < NT; ++tap) {
            int q = k * NT + tap;
            if (q + 1 < 16 * NT) loadA(q + 1, afB);
            f16x8 bf[4];
#pragma unroll
            for (int n = 0; n < 4; ++n) {
                int r = wn * 64 + n * 16 + lr + offs[tap] + LB;
                bf[n] = *(const f16x8*)((char*)Xs + ((((r * 4 + kb) ^ (r & 7)) << 4)));
            }
            __builtin_amdgcn_s_setprio(1);
#pragma unroll
            for (int m = 0; m < 4; ++m)
#pragma unroll
                for (int n = 0; n < 4; ++n)
                    acc[m][n] = __builtin_amdgcn_mfma_f32_16x16x32_f16(afA[m], bf[n], acc[m][n], 0, 0, 0);
            __builtin_amdgcn_s_setprio(0);
#pragma unroll
            for (int m = 0; m < 4; ++m) afA[m] = afB[m];
        }
    }
    // epilogue: all invalid positions computed to natural zeros -> store unconditionally
    size_t slab = (size_t)(C * 8 + b) * 512;
#pragma unroll
    for (int m = 0; m < 4; ++m) {
#pragma unroll
        for (int j = 0; j < 4; ++j) {
            int fo = fo0 + wm * 64 + m * 16 + kb * 4 + j;   // C row = (lane>>4)*4 + j
            f16* pb = P + (slab + fo) * PLANE;
#pragma unroll
            for (int n = 0; n < 4; ++n) {
                int nn = n0 + wn * 64 + n * 16 + lr;        // C col = lane & 15
                int t = (nn * 993) >> 16;                   // n / 66
                int s = nn - t * 66;
                pb[(t + 1) * 68 + (s + 1)] = (f16)acc[m][n][j];
            }
        }
    }
}

__global__ __launch_bounds__(256, 3) void tconv2_kernel(const f16* __restrict__ wpar2,
                                                        const f16* __restrict__ xp,
                                                        f16* __restrict__ P) {
    __shared__ __align__(16) f16 Xs[780 * 8];   // 195 rows * 4 units * 16B, swizzled
    int id = blockIdx.x;                        // 4352 = 8b * 4c * 4fg * 34 n-tiles
    int b = id & 7;                             // XCD swizzle: b <-> XCD
    int r = id >> 3;                            // 0..543
    int c = r / 136;
    int r2 = r - c * 136;
    int fg = r2 / 34;
    int n0t = r2 - fg * 34;
    switch (c) {
        case 0: tconv_body<0>(wpar2, xp, P, Xs, b, fg, n0t); break;
        case 1: tconv_body<1>(wpar2, xp, P, Xs, b, fg, n0t); break;
        case 2: tconv_body<2>(wpar2, xp, P, Xs, b, fg, n0t); break;
        default: tconv_body<3>(wpar2, xp, P, Xs, b, fg, n0t); break;
    }
}

// ---------------- pass 2: separable FIR [.25 .75 .75 .25]^2 + demod ----------------
__global__ __launch_bounds__(256) void fir2_kernel(const f16* __restrict__ P,
                                                   const float* __restrict__ demod,
                                                   float* __restrict__ out) {
    int bid = blockIdx.x;          // 8b * 512fo * 8rc = 32768
    int rc = bid & 7;
    int fo = (bid >> 3) & 511;
    int b = bid >> 12;
    int OY0 = rc * 16;

    __shared__ f16 yr[19][2][72];
    int tid = threadIdx.x;
#pragma unroll
    for (int it = 0; it < 3; ++it) {
        int ci = it * 256 + tid;
        if (ci < 646) {                       // 19 rows * 2 px * 17 int2-chunks
            int rr = ci / 34, rem = ci - rr * 34;
            int pxx = rem / 17, ck = rem - pxx * 17;
            int oy = OY0 - 1 + rr;
            int pyy = oy & 1, t = oy >> 1;    // arithmetic shift: oy=-1 -> t=-1 -> row 0 (ring zeros)
            const f16* src = P + ((size_t)((pyy * 2 + pxx) * 8 + b) * 512 + fo) * PLANE
                               + (t + 1) * 68 + ck * 4;
            *(int2*)&yr[rr][pxx][ck * 4] = *(const int2*)src;
        }
    }
    __syncthreads();
    float dm = demod[b * 512 + fo];
    int OX = tid & 127, rg = tid >> 7;
    const float f4[4] = {0.25f, 0.75f, 0.75f, 0.25f};
    float hrow[11];
#pragma unroll
    for (int r = 0; r < 11; ++r) {
        int rr = rg * 8 + r;
        float h = 0.f;
#pragma unroll
        for (int bb = 0; bb < 4; ++bb) {
            int ox = OX - 1 + bb;
            h += f4[bb] * (float)yr[rr][ox & 1][(ox >> 1) + 1];
        }
        hrow[r] = h;
    }
    size_t ob = ((size_t)(b * 512 + fo)) * 128 * 128 + (size_t)OY0 * 128 + OX;
#pragma unroll
    for (int i = 0; i < 8; ++i) {
        float a = f4[0] * hrow[i] + f4[1] * hrow[i + 1] + f4[2] * hrow[i + 2] + f4[3] * hrow[i + 3];
        out[ob + (size_t)(rg * 8 + i) * 128] = a * dm;
    }
}

extern "C" void kernel_launch(void* const* d_in, const int* in_sizes, int n_in,
                              void* d_out, int out_size, void* d_ws, size_t ws_size,
                              hipStream_t stream) {
    const float* x = (const float*)d_in[0];
    const float* style = (const float*)d_in[1];
    const float* w = (const float*)d_in[2];
    const float* mod_w = (const float*)d_in[3];
    const float* mod_b = (const float*)d_in[4];
    float* out = (float*)d_out;

    char* ws = (char*)d_ws;
    float* smod = (float*)(ws + OFF_SMOD);
    float* ssq = (float*)(ws + OFF_SSQ);
    float* demod = (float*)(ws + OFF_DEMOD);
    float* wsq = (float*)(ws + OFF_WSQ);
    f16* wpar2 = (f16*)(ws + OFF_WPAR);
    f16* xp = (f16*)(ws + OFF_XP);
    f16* P = (f16*)(ws + OFF_YP);

    style_kernel<<<8, 512, 0, stream>>>(style, mod_w, mod_b, smod, ssq);
    wsq_kernel<<<512, 512, 0, stream>>>(w, wsq);
    demod_kernel<<<16, 256, 0, stream>>>(ssq, wsq, demod);
    wpar2_kernel<<<512, 256, 0, stream>>>(w, wpar2);
    hipMemsetAsync(xp, 0, XP_BYTES, stream);
    xp_kernel<<<4096, 256, 0, stream>>>(x, smod, xp);
    ring2_kernel<<<8512, 256, 0, stream>>>(P);
    tconv2_kernel<<<4352, 256, 0, stream>>>(wpar2, xp, P);
    fir2_kernel<<<32768, 256, 0, stream>>>(P, demod, out);
}